// Round 21
// baseline (106.546 us; speedup 1.0000x reference)
//
#include <hip/hip_runtime.h>
#include <hip/hip_bf16.h>

// C[1024,16384] = l2norm_rows(inputs[1024,2048]) @ features[16384,2048]^T / 0.05
// Round 21: the 4-phase/K-tile experiment (3x infra-killed, never measured).
// 256x256 GEMM, 8 barriers/tile (was 16), 32 MFMA per barrier-pair.
// Phase = 12 ds_read + 2 stage calls -> barrier -> lgkmcnt(0) -> 32 MFMA ->
// vmcnt(8) -> barrier. Ledger audited (comments). Prep unchanged from R16.

typedef short bf16x8 __attribute__((ext_vector_type(8)));
typedef float f32x4  __attribute__((ext_vector_type(4)));

#define D_K   2048
#define N_N   16384
#define M_M   1024
#define TEMP_INV 20.0f

__device__ __forceinline__ unsigned short f2bf(float f) {
    unsigned u = __builtin_bit_cast(unsigned, f);
    u += 0x7FFFu + ((u >> 16) & 1u);   // round-to-nearest-even (finite data)
    return (unsigned short)(u >> 16);
}

#define GLOAD16(g, l) __builtin_amdgcn_global_load_lds(                        \
    (const __attribute__((address_space(1))) unsigned int*)(g),                \
    (__attribute__((address_space(3))) unsigned int*)(l), 16, 0, 0)

// ---------------- pass 1: prep = anorm (blocks 0..1023) + bconv (rest) ----
__global__ __launch_bounds__(256) void prep_kernel(const float* __restrict__ x,
                                                   const float* __restrict__ B,
                                                   unsigned short* __restrict__ abf,
                                                   unsigned short* __restrict__ bbf) {
    int t = threadIdx.x;
    if (blockIdx.x < M_M) {
        int row = blockIdx.x;
        const float4* xr = reinterpret_cast<const float4*>(x + (size_t)row * D_K);
        float4 a = xr[t * 2];
        float4 b = xr[t * 2 + 1];
        float s = a.x*a.x + a.y*a.y + a.z*a.z + a.w*a.w
                + b.x*b.x + b.y*b.y + b.z*b.z + b.w*b.w;
        #pragma unroll
        for (int off = 32; off > 0; off >>= 1) s += __shfl_down(s, off);
        __shared__ float ps[4];
        __shared__ float sbc;
        if ((t & 63) == 0) ps[t >> 6] = s;
        __syncthreads();
        if (t == 0) {
            float tot = ps[0] + ps[1] + ps[2] + ps[3];
            sbc = 1.0f / fmaxf(sqrtf(tot), 1e-12f);
        }
        __syncthreads();
        float rs = sbc;
        bf16x8 v;
        v[0] = (short)f2bf(a.x * rs); v[1] = (short)f2bf(a.y * rs);
        v[2] = (short)f2bf(a.z * rs); v[3] = (short)f2bf(a.w * rs);
        v[4] = (short)f2bf(b.x * rs); v[5] = (short)f2bf(b.y * rs);
        v[6] = (short)f2bf(b.z * rs); v[7] = (short)f2bf(b.w * rs);
        *reinterpret_cast<bf16x8*>(abf + (size_t)row * D_K + t * 8) = v;
    } else {
        const size_t nv = (size_t)N_N * D_K / 8;
        size_t stride = (size_t)(gridDim.x - M_M) * blockDim.x;
        for (size_t v = (size_t)(blockIdx.x - M_M) * blockDim.x + t; v < nv; v += stride) {
            const float4* p = reinterpret_cast<const float4*>(B) + v * 2;
            float4 a = p[0], b = p[1];
            bf16x8 o;
            o[0] = (short)f2bf(a.x); o[1] = (short)f2bf(a.y);
            o[2] = (short)f2bf(a.z); o[3] = (short)f2bf(a.w);
            o[4] = (short)f2bf(b.x); o[5] = (short)f2bf(b.y);
            o[6] = (short)f2bf(b.z); o[7] = (short)f2bf(b.w);
            reinterpret_cast<bf16x8*>(bbf)[v] = o;
        }
    }
}

// ---------------- pass 2: 256x256 GEMM, 4 phases/tile ---------------------
// 512 threads = 8 waves (2M x 4N); wave tile 128x64. LDS 128K = buf[2] x
// {A 32K, B 32K}; region (mat,s) = 256 x 32 bf16 = 16K.
// Tile T (buf b): P1(s=0): 12 ds_read + stage{A,B}-k1(T+1)->buf^1 ->
//   barrier -> lgkm0 -> 32 MFMA -> vmcnt(8) -> barrier.
// P2(s=1): 12 ds_read + stage{A,B}-k0(T+2)->buf -> same tail.
// Ledger (8 ops/tile, vmcnt(8) each phase end): P1-post certifies k1(T)
// (staged T-1.P1, >=8 ops old) before P2 reads; P2-post certifies k0(T+1)
// (staged T-1.P2) before T+1.P1 reads. WAR: P2's stage into buf-s0 follows
// P1's end-barrier (reads drained at P1's lgkm0); k1 stage targets buf^1
// (last read T-1.P2, barrier between). Tail clamp -> dead regions (audited).
__global__ __launch_bounds__(512, 2) void gemm4_kernel(const unsigned short* __restrict__ Abf,
                                                       const unsigned short* __restrict__ Bbf,
                                                       float* __restrict__ C) {
    __shared__ __align__(16) unsigned short lds[65536];   // 128 KiB

    // 256 wgs = 4 Mtiles x 64 Ntiles; bijective XCD swizzle (256 % 8 == 0).
    int bid = blockIdx.x;
    int wg  = (bid & 7) * 32 + (bid >> 3);
    int tm  = wg & 3, tn = wg >> 2;
    int m_blk = tm * 256, n_blk = tn * 256;

    int t = threadIdx.x, lane = t & 63, w = t >> 6;
    int wm = w >> 2, wn = w & 3;                     // 2 x 4 wave grid

    // ds_read lane constants (R5/R8-verified): slot = q ^ ((row>>1)&3)
    int l15  = lane & 15;
    int slot = ((lane >> 4) ^ ((l15 >> 1) & 3)) * 16;     // byte slot offset
    int aoff[8], boff;
    #pragma unroll
    for (int f = 0; f < 8; ++f)
        aoff[f] = (wm * 128 + f * 16 + l15) * 64 + slot;  // f covers both mh
    boff = (wn * 64 + l15) * 64 + slot;

    // stage source pointers (pre-swizzled global chunk per rule #21)
    const unsigned short* gA[2];
    const unsigned short* gB[2];
    int sdst[2];
    #pragma unroll
    for (int pass = 0; pass < 2; ++pass) {
        int r = pass * 128 + (t >> 2);
        int csrc = (t & 3) ^ ((r >> 1) & 3);
        gA[pass] = Abf + (size_t)(m_blk + r) * D_K + csrc * 8;
        gB[pass] = Bbf + (size_t)(n_blk + r) * D_K + csrc * 8;
        sdst[pass] = pass * 8192 + w * 1024;   // wave-uniform LDS dest base
    }

    // stage one half-tile: region (mat, s) of K-tile kt into buffer b (2 ops)
    auto stage = [&](int mat, int s, int b, int ktile) {
        int kt = ktile < 32 ? ktile : 31;              // tail clamp (dead regions)
        int koff = kt * 64 + s * 32;
        int ldsb = b * 65536 + mat * 32768 + s * 16384;
        GLOAD16((mat ? gB[0] : gA[0]) + koff, (char*)lds + ldsb + sdst[0]);
        GLOAD16((mat ? gB[1] : gA[1]) + koff, (char*)lds + ldsb + sdst[1]);
    };

    f32x4 acc[8][4] = {};

#define PHASE4(b, s, stS, stB, stKt)                                           \
    {                                                                          \
        bf16x8 af[8], bfr[4];                                                  \
        _Pragma("unroll")                                                      \
        for (int f = 0; f < 8; ++f)                                            \
            af[f] = *reinterpret_cast<const bf16x8*>(                          \
                (char*)lds + (b) * 65536 + (s) * 16384 + aoff[f]);             \
        _Pragma("unroll")                                                      \
        for (int n = 0; n < 4; ++n)                                            \
            bfr[n] = *reinterpret_cast<const bf16x8*>(                         \
                (char*)lds + (b) * 65536 + 32768 + (s) * 16384 + boff +        \
                n * 1024);                                                     \
        stage(0, stS, stB, stKt);                                              \
        stage(1, stS, stB, stKt);                                              \
        asm volatile("s_barrier" ::: "memory");                                \
        asm volatile("s_waitcnt lgkmcnt(0)" ::: "memory");                     \
        __builtin_amdgcn_sched_barrier(0);                                     \
        __builtin_amdgcn_s_setprio(1);                                         \
        _Pragma("unroll")                                                      \
        for (int f = 0; f < 8; ++f) {                                          \
            _Pragma("unroll")                                                  \
            for (int n = 0; n < 4; ++n)                                        \
                acc[f][n] = __builtin_amdgcn_mfma_f32_16x16x32_bf16(           \
                    af[f], bfr[n], acc[f][n], 0, 0, 0);                        \
        }                                                                      \
        __builtin_amdgcn_s_setprio(0);                                         \
        asm volatile("s_waitcnt vmcnt(8)" ::: "memory");                       \
        asm volatile("s_barrier" ::: "memory");                                \
    }

    // prologue: K0 full + K1 k0-halves (12 ops); vmcnt(8) certifies k0(0)
    stage(0, 0, 0, 0);   // A-k0(0) -> buf0
    stage(1, 0, 0, 0);   // B-k0(0)
    stage(0, 1, 0, 0);   // A-k1(0)
    stage(1, 1, 0, 0);   // B-k1(0)
    stage(0, 0, 1, 1);   // A-k0(1) -> buf1
    stage(1, 0, 1, 1);   // B-k0(1)
    asm volatile("s_waitcnt vmcnt(8)" ::: "memory");
    asm volatile("s_barrier" ::: "memory");

    for (int T = 0; T < 32; ++T) {
        int b = T & 1;
        PHASE4(b, 0, 1, b ^ 1, T + 1)   // stage A+B k1(T+1) -> other buffer
        PHASE4(b, 1, 0, b,     T + 2)   // stage A+B k0(T+2) -> this buffer
    }
#undef PHASE4

    // epilogue: C/D layout col=lane&15, row=(lane>>4)*4+j [m89-verified]
    #pragma unroll
    for (int f = 0; f < 8; ++f) {
        int r = m_blk + wm * 128 + f * 16 + (lane >> 4) * 4;
        #pragma unroll
        for (int j = 0; j < 4; ++j) {
            float* cp = C + (size_t)(r + j) * N_N + n_blk + wn * 64 + l15;
            #pragma unroll
            for (int n = 0; n < 4; ++n)
                cp[n * 16] = acc[f][n][j] * TEMP_INV;
        }
    }
}

// ================= fallback (round-1 fused fp32-staged kernel) ============
__global__ __launch_bounds__(256) void rnorm_kernel(const float* __restrict__ x,
                                                    float* __restrict__ rn) {
    int row = blockIdx.x;
    const float4* xr = reinterpret_cast<const float4*>(x + (size_t)row * D_K);
    int t = threadIdx.x;
    float4 a = xr[t];
    float4 b = xr[t + 256];
    float s = a.x*a.x + a.y*a.y + a.z*a.z + a.w*a.w
            + b.x*b.x + b.y*b.y + b.z*b.z + b.w*b.w;
    #pragma unroll
    for (int off = 32; off > 0; off >>= 1) s += __shfl_down(s, off);
    __shared__ float ps[4];
    int wave = t >> 6, lane = t & 63;
    if (lane == 0) ps[wave] = s;
    __syncthreads();
    if (t == 0) {
        float tot = ps[0] + ps[1] + ps[2] + ps[3];
        rn[row] = 1.0f / fmaxf(sqrtf(tot), 1e-12f);
    }
}

__global__ __launch_bounds__(256, 2) void gemm_kernel(const float* __restrict__ A,
                                                      const float* __restrict__ Bm,
                                                      const float* __restrict__ rn,
                                                      float* __restrict__ C) {
    constexpr int BK = 64;
    __shared__ __align__(16) short lAs[128 * BK];
    __shared__ __align__(16) short lBs[128 * BK];
    int bid = blockIdx.x;
    int nb  = (bid & 7) * 128 + (bid >> 3);
    int tm  = nb & 7;
    int tn  = nb >> 3;
    int m0 = tm * 128, n0 = tn * 128;
    int t = threadIdx.x;
    int lane = t & 63, w = t >> 6;
    int wr = (w >> 1) * 64, wc = (w & 1) * 64;
    f32x4 acc[4][4] = {};
    float4 ra[4][2], rb[4][2];
    float  sc[4];
    int    srow[4], sgrp[4];
    #pragma unroll
    for (int i = 0; i < 4; ++i) {
        int li = t + i * 256;
        srow[i] = li >> 3;
        sgrp[i] = li & 7;
        sc[i]   = rn[m0 + srow[i]];
    }
    auto load_tiles = [&](int kt) {
        int k0 = kt * BK;
        #pragma unroll
        for (int i = 0; i < 4; ++i) {
            const float4* pa = reinterpret_cast<const float4*>(
                A + (size_t)(m0 + srow[i]) * D_K + k0 + sgrp[i] * 8);
            ra[i][0] = pa[0]; ra[i][1] = pa[1];
            const float4* pb = reinterpret_cast<const float4*>(
                Bm + (size_t)(n0 + srow[i]) * D_K + k0 + sgrp[i] * 8);
            rb[i][0] = pb[0]; rb[i][1] = pb[1];
        }
    };
    auto write_tiles = [&]() {
        #pragma unroll
        for (int i = 0; i < 4; ++i) {
            int row = srow[i];
            int slotw = sgrp[i] ^ (row & 7);
            float s = sc[i];
            bf16x8 va, vb;
            va[0] = (short)f2bf(ra[i][0].x * s); va[1] = (short)f2bf(ra[i][0].y * s);
            va[2] = (short)f2bf(ra[i][0].z * s); va[3] = (short)f2bf(ra[i][0].w * s);
            va[4] = (short)f2bf(ra[i][1].x * s); va[5] = (short)f2bf(ra[i][1].y * s);
            va[6] = (short)f2bf(ra[i][1].z * s); va[7] = (short)f2bf(ra[i][1].w * s);
            vb[0] = (short)f2bf(rb[i][0].x); vb[1] = (short)f2bf(rb[i][0].y);
            vb[2] = (short)f2bf(rb[i][0].z); vb[3] = (short)f2bf(rb[i][0].w);
            vb[4] = (short)f2bf(rb[i][1].x); vb[5] = (short)f2bf(rb[i][1].y);
            vb[6] = (short)f2bf(rb[i][1].z); vb[7] = (short)f2bf(rb[i][1].w);
            *reinterpret_cast<bf16x8*>(&lAs[row * BK + slotw * 8]) = va;
            *reinterpret_cast<bf16x8*>(&lBs[row * BK + slotw * 8]) = vb;
        }
    };
    auto compute = [&]() {
        #pragma unroll
        for (int ks = 0; ks < 2; ++ks) {
            bf16x8 af[4], bfr[4];
            #pragma unroll
            for (int f = 0; f < 4; ++f) {
                int arow = wr + f * 16 + (lane & 15);
                int aslot = (ks * 4 + (lane >> 4)) ^ (arow & 7);
                af[f] = *reinterpret_cast<const bf16x8*>(&lAs[arow * BK + aslot * 8]);
                int brow = wc + f * 16 + (lane & 15);
                int bslot = (ks * 4 + (lane >> 4)) ^ (brow & 7);
                bfr[f] = *reinterpret_cast<const bf16x8*>(&lBs[brow * BK + bslot * 8]);
            }
            #pragma unroll
            for (int m = 0; m < 4; ++m)
                #pragma unroll
                for (int n = 0; n < 4; ++n)
                    acc[m][n] = __builtin_amdgcn_mfma_f32_16x16x32_bf16(
                        af[m], bfr[n], acc[m][n], 0, 0, 0);
        }
    };
    load_tiles(0);
    write_tiles();
    for (int kt = 1; kt < D_K / BK; ++kt) {
        __syncthreads();
        load_tiles(kt);
        compute();
        __syncthreads();
        write_tiles();
    }
    __syncthreads();
    compute();
    #pragma unroll
    for (int m = 0; m < 4; ++m) {
        int r = m0 + wr + m * 16 + (lane >> 4) * 4;
        #pragma unroll
        for (int j = 0; j < 4; ++j) {
            float* cp = C + (size_t)(r + j) * N_N + n0 + wc + (lane & 15);
            #pragma unroll
            for (int n = 0; n < 4; ++n)
                cp[n * 16] = acc[m][n][j] * TEMP_INV;
        }
    }
}

extern "C" void kernel_launch(void* const* d_in, const int* in_sizes, int n_in,
                              void* d_out, int out_size, void* d_ws, size_t ws_size,
                              hipStream_t stream) {
    const float* inputs   = (const float*)d_in[0];
    // d_in[1] = targets (unused by the forward output)
    const float* features = (const float*)d_in[2];
    float* out = (float*)d_out;

    const size_t needA = (size_t)M_M * D_K * 2;           // 4 MiB
    const size_t needB = (size_t)N_N * D_K * 2;           // 64 MiB
    if (ws_size >= needA + needB) {
        unsigned short* Abf = (unsigned short*)d_ws;
        unsigned short* Bbf = Abf + (size_t)M_M * D_K;
        prep_kernel<<<M_M + 2048, 256, 0, stream>>>(inputs, features, Abf, Bbf);
        gemm4_kernel<<<(M_M / 256) * (N_N / 256), 512, 0, stream>>>(Abf, Bbf, out);
    } else {
        float* rn = (float*)d_ws;   // 1024 floats
        rnorm_kernel<<<M_M, 256, 0, stream>>>(inputs, rn);
        gemm_kernel<<<(M_M / 128) * (N_N / 128), 256, 0, stream>>>(inputs, features, rn, out);
    }
}

// Round 22
// 104.018 us; speedup vs baseline: 1.0243x; 1.0243x over previous
//
#include <hip/hip_runtime.h>
#include <hip/hip_bf16.h>

// C[1024,16384] = l2norm_rows(inputs[1024,2048]) @ features[16384,2048]^T / 0.05
// FINAL (R16-verified, 103.44 us): prep (anorm+bconv fused, HBM-roofline) +
// 256x256 8-phase GEMM (global_load_lds(16), both-sides XOR swizzle,
// counted vmcnt, setprio). 7 structural variants measured worse; the
// fine-phase/16-barrier structure wins via wave-level pipe overlap (m114).

typedef short bf16x8 __attribute__((ext_vector_type(8)));
typedef float f32x4  __attribute__((ext_vector_type(4)));

#define D_K   2048
#define N_N   16384
#define M_M   1024
#define TEMP_INV 20.0f

__device__ __forceinline__ unsigned short f2bf(float f) {
    unsigned u = __builtin_bit_cast(unsigned, f);
    u += 0x7FFFu + ((u >> 16) & 1u);   // round-to-nearest-even (finite data)
    return (unsigned short)(u >> 16);
}

#define GLOAD16(g, l) __builtin_amdgcn_global_load_lds(                        \
    (const __attribute__((address_space(1))) unsigned int*)(g),                \
    (__attribute__((address_space(3))) unsigned int*)(l), 16, 0, 0)

// ---------------- pass 1: prep = anorm (blocks 0..1023) + bconv (rest) ----
__global__ __launch_bounds__(256) void prep_kernel(const float* __restrict__ x,
                                                   const float* __restrict__ B,
                                                   unsigned short* __restrict__ abf,
                                                   unsigned short* __restrict__ bbf) {
    int t = threadIdx.x;
    if (blockIdx.x < M_M) {
        int row = blockIdx.x;
        const float4* xr = reinterpret_cast<const float4*>(x + (size_t)row * D_K);
        float4 a = xr[t * 2];
        float4 b = xr[t * 2 + 1];
        float s = a.x*a.x + a.y*a.y + a.z*a.z + a.w*a.w
                + b.x*b.x + b.y*b.y + b.z*b.z + b.w*b.w;
        #pragma unroll
        for (int off = 32; off > 0; off >>= 1) s += __shfl_down(s, off);
        __shared__ float ps[4];
        __shared__ float sbc;
        if ((t & 63) == 0) ps[t >> 6] = s;
        __syncthreads();
        if (t == 0) {
            float tot = ps[0] + ps[1] + ps[2] + ps[3];
            sbc = 1.0f / fmaxf(sqrtf(tot), 1e-12f);
        }
        __syncthreads();
        float rs = sbc;
        bf16x8 v;
        v[0] = (short)f2bf(a.x * rs); v[1] = (short)f2bf(a.y * rs);
        v[2] = (short)f2bf(a.z * rs); v[3] = (short)f2bf(a.w * rs);
        v[4] = (short)f2bf(b.x * rs); v[5] = (short)f2bf(b.y * rs);
        v[6] = (short)f2bf(b.z * rs); v[7] = (short)f2bf(b.w * rs);
        *reinterpret_cast<bf16x8*>(abf + (size_t)row * D_K + t * 8) = v;
    } else {
        const size_t nv = (size_t)N_N * D_K / 8;
        size_t stride = (size_t)(gridDim.x - M_M) * blockDim.x;
        for (size_t v = (size_t)(blockIdx.x - M_M) * blockDim.x + t; v < nv; v += stride) {
            const float4* p = reinterpret_cast<const float4*>(B) + v * 2;
            float4 a = p[0], b = p[1];
            bf16x8 o;
            o[0] = (short)f2bf(a.x); o[1] = (short)f2bf(a.y);
            o[2] = (short)f2bf(a.z); o[3] = (short)f2bf(a.w);
            o[4] = (short)f2bf(b.x); o[5] = (short)f2bf(b.y);
            o[6] = (short)f2bf(b.z); o[7] = (short)f2bf(b.w);
            reinterpret_cast<bf16x8*>(bbf)[v] = o;
        }
    }
}

// ---------------- pass 2: 256x256 8-phase GEMM (R16-verified) -------------
// Ledger: 8 stage-ops issued per K-tile (4 stage calls x 2). Single
// vmcnt(4) at P2-post of tile T: 4 newest = k1(T+1) stay; retires k1(T)
// (read T.P3/P4 after barrier) and k0(T+1) (read T+1.P1/P2). k1(T+1) is
// certified by T+1's P2 wait before its P3 read. WAR: every stage targets
// a region >=1 barrier after its last read. Tail clamp -> dead regions.
__global__ __launch_bounds__(512, 2) void gemm8_kernel(const unsigned short* __restrict__ Abf,
                                                       const unsigned short* __restrict__ Bbf,
                                                       float* __restrict__ C) {
    __shared__ __align__(16) unsigned short lds[65536];   // 128 KiB

    // 256 wgs = 4 Mtiles x 64 Ntiles; bijective XCD swizzle (256 % 8 == 0).
    int bid = blockIdx.x;
    int wg  = (bid & 7) * 32 + (bid >> 3);
    int tm  = wg & 3, tn = wg >> 2;
    int m_blk = tm * 256, n_blk = tn * 256;

    int t = threadIdx.x, lane = t & 63, w = t >> 6;
    int wm = w >> 2, wn = w & 3;                     // 2 x 4 wave grid

    // ds_read lane constants: slot = chunk ^ ((row>>1)&3)
    int l15  = lane & 15;
    int slot = ((lane >> 4) ^ ((l15 >> 1) & 3)) * 16;     // byte slot offset
    int aoff = (wm * 128 + l15) * 64 + slot;              // A region byte off
    int boff = (wn * 64  + l15) * 64 + slot;              // B region byte off

    // stage source pointers (pre-swizzled global chunk per rule #21)
    const unsigned short* gA[2];
    const unsigned short* gB[2];
    int sdst[2];
    #pragma unroll
    for (int pass = 0; pass < 2; ++pass) {
        int r = pass * 128 + (t >> 2);
        int csrc = (t & 3) ^ ((r >> 1) & 3);
        gA[pass] = Abf + (size_t)(m_blk + r) * D_K + csrc * 8;
        gB[pass] = Bbf + (size_t)(n_blk + r) * D_K + csrc * 8;
        sdst[pass] = pass * 8192 + w * 1024;   // wave-uniform LDS dest base
    }

    // stage one half-tile: region (mat, s) of K-tile kt into buffer b
    auto stage = [&](int mat, int s, int b, int ktile) {
        int kt = ktile < 32 ? ktile : 31;              // tail clamp (dead regions)
        int koff = kt * 64 + s * 32;
        int ldsb = b * 65536 + mat * 32768 + s * 16384;
        GLOAD16((mat ? gB[0] : gA[0]) + koff, (char*)lds + ldsb + sdst[0]);
        GLOAD16((mat ? gB[1] : gA[1]) + koff, (char*)lds + ldsb + sdst[1]);
    };

    f32x4 acc[8][4] = {};
    bf16x8 bfr[4];                                     // persists across phase pairs

#define VM4 asm volatile("s_waitcnt vmcnt(4)" ::: "memory")

#define PHASE(b, mh, s, LOADB, stMat, stS, stB, stKt, POST)                    \
    {                                                                          \
        bf16x8 af[4];                                                          \
        _Pragma("unroll")                                                      \
        for (int f = 0; f < 4; ++f)                                            \
            af[f] = *reinterpret_cast<const bf16x8*>(                          \
                (char*)lds + (b) * 65536 + (s) * 16384 + aoff +                \
                ((mh) * 64 + f * 16) * 64);                                    \
        if (LOADB) {                                                           \
            _Pragma("unroll")                                                  \
            for (int n = 0; n < 4; ++n)                                        \
                bfr[n] = *reinterpret_cast<const bf16x8*>(                     \
                    (char*)lds + (b) * 65536 + 32768 + (s) * 16384 + boff +    \
                    n * 1024);                                                 \
        }                                                                      \
        stage(stMat, stS, stB, stKt);                                          \
        asm volatile("s_barrier" ::: "memory");                                \
        asm volatile("s_waitcnt lgkmcnt(0)" ::: "memory");                     \
        __builtin_amdgcn_sched_barrier(0);                                     \
        __builtin_amdgcn_s_setprio(1);                                         \
        _Pragma("unroll")                                                      \
        for (int f = 0; f < 4; ++f) {                                          \
            _Pragma("unroll")                                                  \
            for (int n = 0; n < 4; ++n)                                        \
                acc[(mh) * 4 + f][n] = __builtin_amdgcn_mfma_f32_16x16x32_bf16(\
                    af[f], bfr[n], acc[(mh) * 4 + f][n], 0, 0, 0);             \
        }                                                                      \
        __builtin_amdgcn_s_setprio(0);                                         \
        POST;                                                                  \
        asm volatile("s_barrier" ::: "memory");                                \
    }

    // prologue: K0 full + K1 k0-halves; vmcnt(8) -> oldest 4 ops (K0 k0) landed
    stage(0, 0, 0, 0);   // A-k0(0) -> buf0
    stage(1, 0, 0, 0);   // B-k0(0)
    stage(0, 1, 0, 0);   // A-k1(0)
    stage(1, 1, 0, 0);   // B-k1(0)
    stage(0, 0, 1, 1);   // A-k0(1) -> buf1
    stage(1, 0, 1, 1);   // B-k0(1)
    asm volatile("s_waitcnt vmcnt(8)" ::: "memory");
    asm volatile("s_barrier" ::: "memory");

    for (int u = 0; u < 16; ++u) {
        int t1 = 2 * u + 1;
        // K-tile 2u (buf0)
        PHASE(0, 0, 0, true,  0, 1, 1, t1,     (void)0)   // stage A-k1(t1)->buf1
        PHASE(0, 1, 0, false, 1, 1, 1, t1,     VM4    )   // stage B-k1(t1)->buf1
        PHASE(0, 0, 1, true,  0, 0, 0, t1 + 1, (void)0)   // stage A-k0(t1+1)->buf0
        PHASE(0, 1, 1, false, 1, 0, 0, t1 + 1, (void)0)   // stage B-k0(t1+1)->buf0
        // K-tile 2u+1 (buf1)
        PHASE(1, 0, 0, true,  0, 1, 0, t1 + 1, (void)0)   // stage A-k1(t1+1)->buf0
        PHASE(1, 1, 0, false, 1, 1, 0, t1 + 1, VM4    )   // stage B-k1(t1+1)->buf0
        PHASE(1, 0, 1, true,  0, 0, 1, t1 + 2, (void)0)   // stage A-k0(t1+2)->buf1
        PHASE(1, 1, 1, false, 1, 0, 1, t1 + 2, (void)0)   // stage B-k0(t1+2)->buf1
    }
#undef PHASE
#undef VM4

    // epilogue: C/D layout col=lane&15, row=(lane>>4)*4+j [m89-verified]
    #pragma unroll
    for (int f = 0; f < 8; ++f) {
        int r = m_blk + wm * 128 + (f >> 2) * 64 + (f & 3) * 16 + (lane >> 4) * 4;
        #pragma unroll
        for (int j = 0; j < 4; ++j) {
            float* cp = C + (size_t)(r + j) * N_N + n_blk + wn * 64 + (lane & 15);
            #pragma unroll
            for (int n = 0; n < 4; ++n)
                cp[n * 16] = acc[f][n][j] * TEMP_INV;
        }
    }
}

// ================= fallback (round-1 fused fp32-staged kernel) ============
__global__ __launch_bounds__(256) void rnorm_kernel(const float* __restrict__ x,
                                                    float* __restrict__ rn) {
    int row = blockIdx.x;
    const float4* xr = reinterpret_cast<const float4*>(x + (size_t)row * D_K);
    int t = threadIdx.x;
    float4 a = xr[t];
    float4 b = xr[t + 256];
    float s = a.x*a.x + a.y*a.y + a.z*a.z + a.w*a.w
            + b.x*b.x + b.y*b.y + b.z*b.z + b.w*b.w;
    #pragma unroll
    for (int off = 32; off > 0; off >>= 1) s += __shfl_down(s, off);
    __shared__ float ps[4];
    int wave = t >> 6, lane = t & 63;
    if (lane == 0) ps[wave] = s;
    __syncthreads();
    if (t == 0) {
        float tot = ps[0] + ps[1] + ps[2] + ps[3];
        rn[row] = 1.0f / fmaxf(sqrtf(tot), 1e-12f);
    }
}

__global__ __launch_bounds__(256, 2) void gemm_kernel(const float* __restrict__ A,
                                                      const float* __restrict__ Bm,
                                                      const float* __restrict__ rn,
                                                      float* __restrict__ C) {
    constexpr int BK = 64;
    __shared__ __align__(16) short lAs[128 * BK];
    __shared__ __align__(16) short lBs[128 * BK];
    int bid = blockIdx.x;
    int nb  = (bid & 7) * 128 + (bid >> 3);
    int tm  = nb & 7;
    int tn  = nb >> 3;
    int m0 = tm * 128, n0 = tn * 128;
    int t = threadIdx.x;
    int lane = t & 63, w = t >> 6;
    int wr = (w >> 1) * 64, wc = (w & 1) * 64;
    f32x4 acc[4][4] = {};
    float4 ra[4][2], rb[4][2];
    float  sc[4];
    int    srow[4], sgrp[4];
    #pragma unroll
    for (int i = 0; i < 4; ++i) {
        int li = t + i * 256;
        srow[i] = li >> 3;
        sgrp[i] = li & 7;
        sc[i]   = rn[m0 + srow[i]];
    }
    auto load_tiles = [&](int kt) {
        int k0 = kt * BK;
        #pragma unroll
        for (int i = 0; i < 4; ++i) {
            const float4* pa = reinterpret_cast<const float4*>(
                A + (size_t)(m0 + srow[i]) * D_K + k0 + sgrp[i] * 8);
            ra[i][0] = pa[0]; ra[i][1] = pa[1];
            const float4* pb = reinterpret_cast<const float4*>(
                Bm + (size_t)(n0 + srow[i]) * D_K + k0 + sgrp[i] * 8);
            rb[i][0] = pb[0]; rb[i][1] = pb[1];
        }
    };
    auto write_tiles = [&]() {
        #pragma unroll
        for (int i = 0; i < 4; ++i) {
            int row = srow[i];
            int slotw = sgrp[i] ^ (row & 7);
            float s = sc[i];
            bf16x8 va, vb;
            va[0] = (short)f2bf(ra[i][0].x * s); va[1] = (short)f2bf(ra[i][0].y * s);
            va[2] = (short)f2bf(ra[i][0].z * s); va[3] = (short)f2bf(ra[i][0].w * s);
            va[4] = (short)f2bf(ra[i][1].x * s); va[5] = (short)f2bf(ra[i][1].y * s);
            va[6] = (short)f2bf(ra[i][1].z * s); va[7] = (short)f2bf(ra[i][1].w * s);
            vb[0] = (short)f2bf(rb[i][0].x); vb[1] = (short)f2bf(rb[i][0].y);
            vb[2] = (short)f2bf(rb[i][0].z); vb[3] = (short)f2bf(rb[i][0].w);
            vb[4] = (short)f2bf(rb[i][1].x); vb[5] = (short)f2bf(rb[i][1].y);
            vb[6] = (short)f2bf(rb[i][1].z); vb[7] = (short)f2bf(rb[i][1].w);
            *reinterpret_cast<bf16x8*>(&lAs[row * BK + slotw * 8]) = va;
            *reinterpret_cast<bf16x8*>(&lBs[row * BK + slotw * 8]) = vb;
        }
    };
    auto compute = [&]() {
        #pragma unroll
        for (int ks = 0; ks < 2; ++ks) {
            bf16x8 af[4], bfr[4];
            #pragma unroll
            for (int f = 0; f < 4; ++f) {
                int arow = wr + f * 16 + (lane & 15);
                int aslot = (ks * 4 + (lane >> 4)) ^ (arow & 7);
                af[f] = *reinterpret_cast<const bf16x8*>(&lAs[arow * BK + aslot * 8]);
                int brow = wc + f * 16 + (lane & 15);
                int bslot = (ks * 4 + (lane >> 4)) ^ (brow & 7);
                bfr[f] = *reinterpret_cast<const bf16x8*>(&lBs[brow * BK + bslot * 8]);
            }
            #pragma unroll
            for (int m = 0; m < 4; ++m)
                #pragma unroll
                for (int n = 0; n < 4; ++n)
                    acc[m][n] = __builtin_amdgcn_mfma_f32_16x16x32_bf16(
                        af[m], bfr[n], acc[m][n], 0, 0, 0);
        }
    };
    load_tiles(0);
    write_tiles();
    for (int kt = 1; kt < D_K / BK; ++kt) {
        __syncthreads();
        load_tiles(kt);
        compute();
        __syncthreads();
        write_tiles();
    }
    __syncthreads();
    compute();
    #pragma unroll
    for (int m = 0; m < 4; ++m) {
        int r = m0 + wr + m * 16 + (lane >> 4) * 4;
        #pragma unroll
        for (int j = 0; j < 4; ++j) {
            float* cp = C + (size_t)(r + j) * N_N + n0 + wc + (lane & 15);
            #pragma unroll
            for (int n = 0; n < 4; ++n)
                cp[n * 16] = acc[m][n][j] * TEMP_INV;
        }
    }
}

extern "C" void kernel_launch(void* const* d_in, const int* in_sizes, int n_in,
                              void* d_out, int out_size, void* d_ws, size_t ws_size,
                              hipStream_t stream) {
    const float* inputs   = (const float*)d_in[0];
    // d_in[1] = targets (unused by the forward output)
    const float* features = (const float*)d_in[2];
    float* out = (float*)d_out;

    const size_t needA = (size_t)M_M * D_K * 2;           // 4 MiB
    const size_t needB = (size_t)N_N * D_K * 2;           // 64 MiB
    if (ws_size >= needA + needB) {
        unsigned short* Abf = (unsigned short*)d_ws;
        unsigned short* Bbf = Abf + (size_t)M_M * D_K;
        prep_kernel<<<M_M + 2048, 256, 0, stream>>>(inputs, features, Abf, Bbf);
        gemm8_kernel<<<(M_M / 256) * (N_N / 256), 512, 0, stream>>>(Abf, Bbf, out);
    } else {
        float* rn = (float*)d_ws;   // 1024 floats
        rnorm_kernel<<<M_M, 256, 0, stream>>>(inputs, rn);
        gemm_kernel<<<(M_M / 128) * (N_N / 128), 256, 0, stream>>>(inputs, features, rn, out);
    }
}